// Round 1
// baseline (19242.143 us; speedup 1.0000x reference)
//
#include <hip/hip_runtime.h>

#define T_SEQ  1024
#define NBATCH 512
#define IN_DIM 16
#define HDIM   128
#define G4     (4 * HDIM)

__device__ __forceinline__ float sigf(float x) {
  return __builtin_amdgcn_rcpf(1.0f + __expf(-x));
}
__device__ __forceinline__ float tanhf_fast(float x) {
  // 1 - 2/(1+exp(2x)); saturates correctly at +-inf
  return 1.0f - 2.0f * __builtin_amdgcn_rcpf(1.0f + __expf(2.0f * x));
}

// ---------------- Layer 0: persistent recurrent kernel ----------------
// 256 WGs x 512 threads; WG owns batches {2w, 2w+1}; thread t owns gate row t.
__global__ __launch_bounds__(512, 2) void lstm_l0(
    const float* __restrict__ x, const float* __restrict__ Wih,
    const float* __restrict__ Whh, const float* __restrict__ bih,
    const float* __restrict__ bhh, float* __restrict__ h1state,
    float* __restrict__ c1state, float* __restrict__ h1buf,
    int t0, int Tc)
{
  const int tid = threadIdx.x;
  const int wg  = blockIdx.x;

  float wih[IN_DIM];
  float whh[HDIM];
#pragma unroll
  for (int k = 0; k < IN_DIM; ++k) wih[k] = Wih[tid * IN_DIM + k];
#pragma unroll
  for (int k = 0; k < HDIM; ++k) whh[k] = Whh[tid * HDIM + k];
  const float bias = bih[tid] + bhh[tid];

  __shared__ __align__(16) float xs[2][64][IN_DIM];  // 8 KiB x-stage window
  __shared__ __align__(16) float hs[2][HDIM];
  __shared__ __align__(16) float gs[2][G4];

  const int bb = tid >> 7;   // update-phase batch (threads 0..255)
  const int j  = tid & 127;  // update-phase hidden idx
  float c = 0.0f;
  if (tid < 256) {
    const int bg = wg * 2 + bb;
    hs[bb][j] = h1state[(size_t)bg * HDIM + j];
    c = c1state[(size_t)bg * HDIM + j];
  }
  __syncthreads();

  for (int tt = 0; tt < Tc; ++tt) {
    const int t = t0 + tt;
    if (tt == 0 || (t & 63) == 0) {
      // stage the aligned 64-step x window for both batches (2048 floats)
      const int tb = t & ~63;
      const int sb = tid >> 8;          // which batch this thread stages
      const int f  = (tid & 255) * 4;   // 0..1023 within the batch window
      const int ts = f >> 4;
      const int ii = f & 15;
      const float4 v = *(const float4*)
          &x[((size_t)(wg * 2 + sb) * T_SEQ + (tb + ts)) * IN_DIM + ii];
      *(float4*)&xs[sb][ts][ii] = v;
      __syncthreads();
    }
    const int tl = t & 63;

    float z0 = bias, z1 = bias;
    {
      const float4* xa = (const float4*)xs[0][tl];
      const float4* xb = (const float4*)xs[1][tl];
#pragma unroll
      for (int k = 0; k < IN_DIM / 4; ++k) {
        const float4 a = xa[k], b = xb[k];
        z0 += wih[4*k+0]*a.x + wih[4*k+1]*a.y + wih[4*k+2]*a.z + wih[4*k+3]*a.w;
        z1 += wih[4*k+0]*b.x + wih[4*k+1]*b.y + wih[4*k+2]*b.z + wih[4*k+3]*b.w;
      }
      const float4* ha = (const float4*)hs[0];
      const float4* hb = (const float4*)hs[1];
#pragma unroll
      for (int k = 0; k < HDIM / 4; ++k) {
        const float4 a = ha[k], b = hb[k];
        z0 += whh[4*k+0]*a.x + whh[4*k+1]*a.y + whh[4*k+2]*a.z + whh[4*k+3]*a.w;
        z1 += whh[4*k+0]*b.x + whh[4*k+1]*b.y + whh[4*k+2]*b.z + whh[4*k+3]*b.w;
      }
    }
    gs[0][tid] = z0;
    gs[1][tid] = z1;
    __syncthreads();

    if (tid < 256) {
      const float zi = gs[bb][j];
      const float zf = gs[bb][HDIM + j];
      const float zg = gs[bb][2 * HDIM + j];
      const float zo = gs[bb][3 * HDIM + j];
      const float ig = sigf(zi);
      const float fg = sigf(zf);
      const float gg = tanhf_fast(zg);
      const float og = sigf(zo);
      c = fg * c + ig * gg;
      const float h = og * tanhf_fast(c);
      hs[bb][j] = h;
      h1buf[((size_t)tt * NBATCH + (wg * 2 + bb)) * HDIM + j] = h;
    }
    __syncthreads();
  }

  if (tid < 256) {
    const int bg = wg * 2 + bb;
    h1state[(size_t)bg * HDIM + j] = hs[bb][j];
    c1state[(size_t)bg * HDIM + j] = c;
  }
}

// ---------------- gx1 GEMM: gx1[m, g] = h1[m,:] . Wih1[g,:] + b ----------------
// grid = Tc*2 WGs x 256 threads; thread owns one m-row (A in registers),
// W chunk (128 gates x 128) staged in LDS, read broadcast.
__global__ __launch_bounds__(256, 2) void gemm_gx1(
    const float* __restrict__ h1buf, const float* __restrict__ Wih1,
    const float* __restrict__ bih1, const float* __restrict__ bhh1,
    float* __restrict__ gx1buf)
{
  const int u = threadIdx.x;
  const size_t m = (size_t)blockIdx.x * 256 + u;

  float a[HDIM];
  const float* arow = h1buf + m * HDIM;
#pragma unroll
  for (int k = 0; k < HDIM / 4; ++k) {
    const float4 v = *(const float4*)&arow[4 * k];
    a[4*k+0] = v.x; a[4*k+1] = v.y; a[4*k+2] = v.z; a[4*k+3] = v.w;
  }

  __shared__ __align__(16) float wlds[128][HDIM];  // 64 KiB
  __shared__ float blds[128];
  float* orow = gx1buf + m * G4;

  for (int nc = 0; nc < 4; ++nc) {
    __syncthreads();
#pragma unroll
    for (int i = 0; i < 16; ++i) {
      const int f = i * 1024 + u * 4;
      const int g = f >> 7;
      const int k = f & 127;
      *(float4*)&wlds[g][k] =
          *(const float4*)&Wih1[(size_t)(nc * 128 + g) * HDIM + k];
    }
    if (u < 128) blds[u] = bih1[nc * 128 + u] + bhh1[nc * 128 + u];
    __syncthreads();

    for (int g4 = 0; g4 < 32; ++g4) {
      float accv[4];
#pragma unroll
      for (int q = 0; q < 4; ++q) {
        const int g = g4 * 4 + q;
        float s = blds[g];
        const float4* w4 = (const float4*)wlds[g];
#pragma unroll
        for (int k = 0; k < HDIM / 4; ++k) {
          const float4 w = w4[k];
          s += a[4*k+0]*w.x + a[4*k+1]*w.y + a[4*k+2]*w.z + a[4*k+3]*w.w;
        }
        accv[q] = s;
      }
      float4 acc;
      acc.x = accv[0]; acc.y = accv[1]; acc.z = accv[2]; acc.w = accv[3];
      *(float4*)&orow[nc * 128 + g4 * 4] = acc;
    }
  }
}

// ---------------- Layer 1 + fused FC ----------------
__global__ __launch_bounds__(512, 2) void lstm_l1(
    const float* __restrict__ gx1buf, const float* __restrict__ Whh1,
    const float* __restrict__ Wfc, const float* __restrict__ bfc,
    float* __restrict__ h2state, float* __restrict__ c2state,
    float* __restrict__ out, int t0, int Tc)
{
  const int tid = threadIdx.x;
  const int wg  = blockIdx.x;

  float whh[HDIM];
#pragma unroll
  for (int k = 0; k < HDIM; ++k) whh[k] = Whh1[tid * HDIM + k];

  __shared__ __align__(16) float hs[2][HDIM];
  __shared__ __align__(16) float gs[2][G4];
  __shared__ float pl[4];

  const int bb = tid >> 7;
  const int j  = tid & 127;
  float c = 0.0f, wfc = 0.0f;
  if (tid < 256) {
    const int bg = wg * 2 + bb;
    hs[bb][j] = h2state[(size_t)bg * HDIM + j];
    c = c2state[(size_t)bg * HDIM + j];
    wfc = Wfc[j];
  }
  const float bfcv = bfc[0];
  __syncthreads();

  // software prefetch of the gate-input stream
  float zc0 = gx1buf[((size_t)0 * NBATCH + wg * 2 + 0) * G4 + tid];
  float zc1 = gx1buf[((size_t)0 * NBATCH + wg * 2 + 1) * G4 + tid];

  for (int tt = 0; tt < Tc; ++tt) {
    float zn0 = 0.0f, zn1 = 0.0f;
    if (tt + 1 < Tc) {
      zn0 = gx1buf[((size_t)(tt + 1) * NBATCH + wg * 2 + 0) * G4 + tid];
      zn1 = gx1buf[((size_t)(tt + 1) * NBATCH + wg * 2 + 1) * G4 + tid];
    }
    float z0 = zc0, z1 = zc1;
    {
      const float4* ha = (const float4*)hs[0];
      const float4* hb = (const float4*)hs[1];
#pragma unroll
      for (int k = 0; k < HDIM / 4; ++k) {
        const float4 a = ha[k], b = hb[k];
        z0 += whh[4*k+0]*a.x + whh[4*k+1]*a.y + whh[4*k+2]*a.z + whh[4*k+3]*a.w;
        z1 += whh[4*k+0]*b.x + whh[4*k+1]*b.y + whh[4*k+2]*b.z + whh[4*k+3]*b.w;
      }
    }
    gs[0][tid] = z0;
    gs[1][tid] = z1;
    __syncthreads();

    if (tid < 256) {
      const float zi = gs[bb][j];
      const float zf = gs[bb][HDIM + j];
      const float zg = gs[bb][2 * HDIM + j];
      const float zo = gs[bb][3 * HDIM + j];
      const float ig = sigf(zi);
      const float fg = sigf(zf);
      const float gg = tanhf_fast(zg);
      const float og = sigf(zo);
      c = fg * c + ig * gg;
      const float h = og * tanhf_fast(c);
      hs[bb][j] = h;
      // fused FC: relu(h) . Wfc, wave-reduce 64 lanes
      float p = fmaxf(h, 0.0f) * wfc;
#pragma unroll
      for (int off = 32; off; off >>= 1) p += __shfl_down(p, off);
      if ((tid & 63) == 0) pl[tid >> 6] = p;
    }
    __syncthreads();

    if (tid < 2) {
      const float o = pl[2 * tid] + pl[2 * tid + 1] + bfcv;
      out[(size_t)(wg * 2 + tid) * T_SEQ + (t0 + tt)] = fmaxf(o, 0.0f);
    }
    zc0 = zn0;
    zc1 = zn1;
  }

  if (tid < 256) {
    const int bg = wg * 2 + bb;
    h2state[(size_t)bg * HDIM + j] = hs[bb][j];
    c2state[(size_t)bg * HDIM + j] = c;
  }
}

extern "C" void kernel_launch(void* const* d_in, const int* in_sizes, int n_in,
                              void* d_out, int out_size, void* d_ws, size_t ws_size,
                              hipStream_t stream)
{
  const float* x    = (const float*)d_in[0];
  const float* Wih0 = (const float*)d_in[1];
  const float* Whh0 = (const float*)d_in[2];
  const float* bih0 = (const float*)d_in[3];
  const float* bhh0 = (const float*)d_in[4];
  const float* Wih1 = (const float*)d_in[5];
  const float* Whh1 = (const float*)d_in[6];
  const float* bih1 = (const float*)d_in[7];
  const float* bhh1 = (const float*)d_in[8];
  const float* Wfc  = (const float*)d_in[9];
  const float* bfc  = (const float*)d_in[10];
  float* out = (float*)d_out;

  const size_t stateN = (size_t)NBATCH * HDIM;  // 65536 floats per state buffer
  float* h1s = (float*)d_ws;
  float* c1s = h1s + stateN;
  float* h2s = c1s + stateN;
  float* c2s = h2s + stateN;
  float* h1buf = c2s + stateN;

  // largest power-of-two T chunk that fits the workspace
  int Tc = 128;
  while (Tc > 1) {
    const size_t need =
        (4 * stateN + (size_t)Tc * NBATCH * (HDIM + G4)) * sizeof(float);
    if (need <= ws_size) break;
    Tc >>= 1;
  }
  float* gx1buf = h1buf + (size_t)Tc * NBATCH * HDIM;

  // zero-init recurrent states (h0 = c0 = 0)
  hipMemsetAsync(d_ws, 0, 4 * stateN * sizeof(float), stream);

  for (int t0 = 0; t0 < T_SEQ; t0 += Tc) {
    hipLaunchKernelGGL(lstm_l0, dim3(NBATCH / 2), dim3(512), 0, stream,
                       x, Wih0, Whh0, bih0, bhh0, h1s, c1s, h1buf, t0, Tc);
    hipLaunchKernelGGL(gemm_gx1, dim3(Tc * 2), dim3(256), 0, stream,
                       h1buf, Wih1, bih1, bhh1, gx1buf);
    hipLaunchKernelGGL(lstm_l1, dim3(NBATCH / 2), dim3(512), 0, stream,
                       gx1buf, Whh1, Wfc, bfc, h2s, c2s, out, t0, Tc);
  }
}

// Round 2
// 4607.689 us; speedup vs baseline: 4.1761x; 4.1761x over previous
//
#include <hip/hip_runtime.h>

#define T_SEQ  1024
#define NBATCH 512
#define IN_DIM 16
#define HDIM   128
#define G4     (4 * HDIM)

__device__ __forceinline__ float sigf(float x) {
  return __builtin_amdgcn_rcpf(1.0f + __expf(-x));
}
__device__ __forceinline__ float tanhf_fast(float x) {
  // 1 - 2/(1+exp(2x)); saturates correctly at +-inf
  return 1.0f - 2.0f * __builtin_amdgcn_rcpf(1.0f + __expf(2.0f * x));
}

// ---------------- Layer 0: persistent recurrent kernel ----------------
// 256 WGs x 512 threads; WG owns batches {2w, 2w+1}; thread t owns gate row t.
__global__ __launch_bounds__(512, 2) void lstm_l0(
    const float* __restrict__ x, const float* __restrict__ Wih,
    const float* __restrict__ Whh, const float* __restrict__ bih,
    const float* __restrict__ bhh, float* __restrict__ h1state,
    float* __restrict__ c1state, float* __restrict__ h1buf,
    int t0, int Tc)
{
  const int tid = threadIdx.x;
  const int wg  = blockIdx.x;

  float wih[IN_DIM];
  float whh[HDIM];
#pragma unroll
  for (int k = 0; k < IN_DIM; ++k) wih[k] = Wih[tid * IN_DIM + k];
#pragma unroll
  for (int k = 0; k < HDIM; ++k) whh[k] = Whh[tid * HDIM + k];
  const float bias = bih[tid] + bhh[tid];

  __shared__ __align__(16) float xs[2][64][IN_DIM];  // 8 KiB x-stage window
  __shared__ __align__(16) float hs[2][HDIM];
  __shared__ __align__(16) float gs[2][G4];

  const int bb = tid >> 7;   // update-phase batch (threads 0..255)
  const int j  = tid & 127;  // update-phase hidden idx
  float c = 0.0f;
  if (tid < 256) {
    const int bg = wg * 2 + bb;
    hs[bb][j] = h1state[(size_t)bg * HDIM + j];
    c = c1state[(size_t)bg * HDIM + j];
  }
  __syncthreads();

  for (int tt = 0; tt < Tc; ++tt) {
    const int t = t0 + tt;
    if (tt == 0 || (t & 63) == 0) {
      // stage the aligned 64-step x window for both batches (2048 floats)
      const int tb = t & ~63;
      const int sb = tid >> 8;          // which batch this thread stages
      const int f  = (tid & 255) * 4;   // 0..1023 within the batch window
      const int ts = f >> 4;
      const int ii = f & 15;
      const float4 v = *(const float4*)
          &x[((size_t)(wg * 2 + sb) * T_SEQ + (tb + ts)) * IN_DIM + ii];
      *(float4*)&xs[sb][ts][ii] = v;
      __syncthreads();
    }
    const int tl = t & 63;

    float z0 = bias, z1 = bias;
    {
      const float4* xa = (const float4*)xs[0][tl];
      const float4* xb = (const float4*)xs[1][tl];
#pragma unroll
      for (int k = 0; k < IN_DIM / 4; ++k) {
        const float4 a = xa[k], b = xb[k];
        z0 += wih[4*k+0]*a.x + wih[4*k+1]*a.y + wih[4*k+2]*a.z + wih[4*k+3]*a.w;
        z1 += wih[4*k+0]*b.x + wih[4*k+1]*b.y + wih[4*k+2]*b.z + wih[4*k+3]*b.w;
      }
      const float4* ha = (const float4*)hs[0];
      const float4* hb = (const float4*)hs[1];
#pragma unroll
      for (int k = 0; k < HDIM / 4; ++k) {
        const float4 a = ha[k], b = hb[k];
        z0 += whh[4*k+0]*a.x + whh[4*k+1]*a.y + whh[4*k+2]*a.z + whh[4*k+3]*a.w;
        z1 += whh[4*k+0]*b.x + whh[4*k+1]*b.y + whh[4*k+2]*b.z + whh[4*k+3]*b.w;
      }
    }
    gs[0][tid] = z0;
    gs[1][tid] = z1;
    __syncthreads();

    if (tid < 256) {
      const float zi = gs[bb][j];
      const float zf = gs[bb][HDIM + j];
      const float zg = gs[bb][2 * HDIM + j];
      const float zo = gs[bb][3 * HDIM + j];
      const float ig = sigf(zi);
      const float fg = sigf(zf);
      const float gg = tanhf_fast(zg);
      const float og = sigf(zo);
      c = fg * c + ig * gg;
      const float h = og * tanhf_fast(c);
      hs[bb][j] = h;
      h1buf[((size_t)tt * NBATCH + (wg * 2 + bb)) * HDIM + j] = h;
    }
    __syncthreads();
  }

  if (tid < 256) {
    const int bg = wg * 2 + bb;
    h1state[(size_t)bg * HDIM + j] = hs[bb][j];
    c1state[(size_t)bg * HDIM + j] = c;
  }
}

// ---------------- gx1 GEMM: C[m,g] = h1[m,:] . Wih1[g,:] + bias[g] -----------
// Register-tiled fp32 GEMM. WG tile 128m x 64n, 256 threads (16x16),
// 8x4 micro-tile per thread, K staged in LDS k-major 32 at a time.
#define BM 128
#define BN 64
#define BK 32
#define ASTR 132   // padded k-major stride (floats): 16B-aligned, read-conflict-free
#define BSTR 68

__global__ __launch_bounds__(256, 4) void gemm_gx1(
    const float* __restrict__ h1buf, const float* __restrict__ Wih1,
    const float* __restrict__ bih1, const float* __restrict__ bhh1,
    float* __restrict__ gx1buf)
{
  const int u  = threadIdx.x;
  const int tx = u & 15;   // n dim (4 cols each)
  const int ty = u >> 4;   // m dim (8 rows each)
  const size_t m0 = (size_t)(blockIdx.x >> 3) * BM;
  const int    n0 = (blockIdx.x & 7) * BN;

  __shared__ __align__(16) float As[BK][ASTR];
  __shared__ __align__(16) float Bs[BK][BSTR];

  float acc[8][4] = {};

  for (int k0 = 0; k0 < HDIM; k0 += BK) {
    __syncthreads();
    // stage A slice: 128 rows x 32 k, transposed to k-major
#pragma unroll
    for (int j = 0; j < 4; ++j) {
      const int f  = j * 256 + u;
      const int m  = f >> 3;
      const int k4 = (f & 7) * 4;
      const float4 v =
          *(const float4*)&h1buf[(m0 + m) * HDIM + k0 + k4];
      As[k4 + 0][m] = v.x;
      As[k4 + 1][m] = v.y;
      As[k4 + 2][m] = v.z;
      As[k4 + 3][m] = v.w;
    }
    // stage B slice: 64 gates x 32 k, transposed to k-major
#pragma unroll
    for (int j = 0; j < 2; ++j) {
      const int f  = j * 256 + u;
      const int g  = f >> 3;
      const int k4 = (f & 7) * 4;
      const float4 v =
          *(const float4*)&Wih1[(size_t)(n0 + g) * HDIM + k0 + k4];
      Bs[k4 + 0][g] = v.x;
      Bs[k4 + 1][g] = v.y;
      Bs[k4 + 2][g] = v.z;
      Bs[k4 + 3][g] = v.w;
    }
    __syncthreads();

#pragma unroll 4
    for (int k = 0; k < BK; ++k) {
      const float4 b  = *(const float4*)&Bs[k][tx * 4];
      const float4 a0 = *(const float4*)&As[k][ty * 8];
      const float4 a1 = *(const float4*)&As[k][ty * 8 + 4];
      const float av[8] = {a0.x, a0.y, a0.z, a0.w, a1.x, a1.y, a1.z, a1.w};
      const float bv[4] = {b.x, b.y, b.z, b.w};
#pragma unroll
      for (int i = 0; i < 8; ++i)
#pragma unroll
        for (int q = 0; q < 4; ++q)
          acc[i][q] += av[i] * bv[q];
    }
  }

  const float4 b1 = *(const float4*)&bih1[n0 + tx * 4];
  const float4 b2 = *(const float4*)&bhh1[n0 + tx * 4];
  const float bias[4] = {b1.x + b2.x, b1.y + b2.y, b1.z + b2.z, b1.w + b2.w};

#pragma unroll
  for (int i = 0; i < 8; ++i) {
    float4 o;
    o.x = acc[i][0] + bias[0];
    o.y = acc[i][1] + bias[1];
    o.z = acc[i][2] + bias[2];
    o.w = acc[i][3] + bias[3];
    *(float4*)&gx1buf[(m0 + ty * 8 + i) * G4 + n0 + tx * 4] = o;
  }
}

// ---------------- Layer 1 + fused FC ----------------
__global__ __launch_bounds__(512, 2) void lstm_l1(
    const float* __restrict__ gx1buf, const float* __restrict__ Whh1,
    const float* __restrict__ Wfc, const float* __restrict__ bfc,
    float* __restrict__ h2state, float* __restrict__ c2state,
    float* __restrict__ out, int t0, int Tc)
{
  const int tid = threadIdx.x;
  const int wg  = blockIdx.x;

  float whh[HDIM];
#pragma unroll
  for (int k = 0; k < HDIM; ++k) whh[k] = Whh1[tid * HDIM + k];

  __shared__ __align__(16) float hs[2][HDIM];
  __shared__ __align__(16) float gs[2][G4];
  __shared__ float pl[4];

  const int bb = tid >> 7;
  const int j  = tid & 127;
  float c = 0.0f, wfc = 0.0f;
  if (tid < 256) {
    const int bg = wg * 2 + bb;
    hs[bb][j] = h2state[(size_t)bg * HDIM + j];
    c = c2state[(size_t)bg * HDIM + j];
    wfc = Wfc[j];
  }
  const float bfcv = bfc[0];
  __syncthreads();

  // software prefetch of the gate-input stream
  float zc0 = gx1buf[((size_t)0 * NBATCH + wg * 2 + 0) * G4 + tid];
  float zc1 = gx1buf[((size_t)0 * NBATCH + wg * 2 + 1) * G4 + tid];

  for (int tt = 0; tt < Tc; ++tt) {
    float zn0 = 0.0f, zn1 = 0.0f;
    if (tt + 1 < Tc) {
      zn0 = gx1buf[((size_t)(tt + 1) * NBATCH + wg * 2 + 0) * G4 + tid];
      zn1 = gx1buf[((size_t)(tt + 1) * NBATCH + wg * 2 + 1) * G4 + tid];
    }
    float z0 = zc0, z1 = zc1;
    {
      const float4* ha = (const float4*)hs[0];
      const float4* hb = (const float4*)hs[1];
#pragma unroll
      for (int k = 0; k < HDIM / 4; ++k) {
        const float4 a = ha[k], b = hb[k];
        z0 += whh[4*k+0]*a.x + whh[4*k+1]*a.y + whh[4*k+2]*a.z + whh[4*k+3]*a.w;
        z1 += whh[4*k+0]*b.x + whh[4*k+1]*b.y + whh[4*k+2]*b.z + whh[4*k+3]*b.w;
      }
    }
    gs[0][tid] = z0;
    gs[1][tid] = z1;
    __syncthreads();

    if (tid < 256) {
      const float zi = gs[bb][j];
      const float zf = gs[bb][HDIM + j];
      const float zg = gs[bb][2 * HDIM + j];
      const float zo = gs[bb][3 * HDIM + j];
      const float ig = sigf(zi);
      const float fg = sigf(zf);
      const float gg = tanhf_fast(zg);
      const float og = sigf(zo);
      c = fg * c + ig * gg;
      const float h = og * tanhf_fast(c);
      hs[bb][j] = h;
      // fused FC: relu(h) . Wfc, wave-reduce 64 lanes
      float p = fmaxf(h, 0.0f) * wfc;
#pragma unroll
      for (int off = 32; off; off >>= 1) p += __shfl_down(p, off);
      if ((tid & 63) == 0) pl[tid >> 6] = p;
    }
    __syncthreads();

    if (tid < 2) {
      const float o = pl[2 * tid] + pl[2 * tid + 1] + bfcv;
      out[(size_t)(wg * 2 + tid) * T_SEQ + (t0 + tt)] = fmaxf(o, 0.0f);
    }
    zc0 = zn0;
    zc1 = zn1;
  }

  if (tid < 256) {
    const int bg = wg * 2 + bb;
    h2state[(size_t)bg * HDIM + j] = hs[bb][j];
    c2state[(size_t)bg * HDIM + j] = c;
  }
}

extern "C" void kernel_launch(void* const* d_in, const int* in_sizes, int n_in,
                              void* d_out, int out_size, void* d_ws, size_t ws_size,
                              hipStream_t stream)
{
  const float* x    = (const float*)d_in[0];
  const float* Wih0 = (const float*)d_in[1];
  const float* Whh0 = (const float*)d_in[2];
  const float* bih0 = (const float*)d_in[3];
  const float* bhh0 = (const float*)d_in[4];
  const float* Wih1 = (const float*)d_in[5];
  const float* Whh1 = (const float*)d_in[6];
  const float* bih1 = (const float*)d_in[7];
  const float* bhh1 = (const float*)d_in[8];
  const float* Wfc  = (const float*)d_in[9];
  const float* bfc  = (const float*)d_in[10];
  float* out = (float*)d_out;

  const size_t stateN = (size_t)NBATCH * HDIM;  // 65536 floats per state buffer
  float* h1s = (float*)d_ws;
  float* c1s = h1s + stateN;
  float* h2s = c1s + stateN;
  float* c2s = h2s + stateN;
  float* h1buf = c2s + stateN;

  // largest power-of-two T chunk that fits the workspace
  int Tc = 128;
  while (Tc > 1) {
    const size_t need =
        (4 * stateN + (size_t)Tc * NBATCH * (HDIM + G4)) * sizeof(float);
    if (need <= ws_size) break;
    Tc >>= 1;
  }
  float* gx1buf = h1buf + (size_t)Tc * NBATCH * HDIM;

  // zero-init recurrent states (h0 = c0 = 0)
  hipMemsetAsync(d_ws, 0, 4 * stateN * sizeof(float), stream);

  for (int t0 = 0; t0 < T_SEQ; t0 += Tc) {
    hipLaunchKernelGGL(lstm_l0, dim3(NBATCH / 2), dim3(512), 0, stream,
                       x, Wih0, Whh0, bih0, bhh0, h1s, c1s, h1buf, t0, Tc);
    // grid = (M/BM) * (G4/BN) = (Tc*512/128) * 8 = 32*Tc
    hipLaunchKernelGGL(gemm_gx1, dim3((Tc * NBATCH / BM) * (G4 / BN)),
                       dim3(256), 0, stream,
                       h1buf, Wih1, bih1, bhh1, gx1buf);
    hipLaunchKernelGGL(lstm_l1, dim3(NBATCH / 2), dim3(512), 0, stream,
                       gx1buf, Whh1, Wfc, bfc, h2s, c2s, out, t0, Tc);
  }
}

// Round 3
// 3622.426 us; speedup vs baseline: 5.3119x; 1.2720x over previous
//
#include <hip/hip_runtime.h>

#define T_SEQ  1024
#define NBATCH 512
#define IN_DIM 16
#define HDIM   128
#define G4     (4 * HDIM)

typedef unsigned short ushort_t;
typedef __attribute__((ext_vector_type(8))) short bf16x8;
typedef __attribute__((ext_vector_type(4))) float f32x4;

#define MFMA(a, b, c) __builtin_amdgcn_mfma_f32_16x16x32_bf16((a), (b), (c), 0, 0, 0)

__device__ __forceinline__ float sigf(float x) {
  return __builtin_amdgcn_rcpf(1.0f + __expf(-x));
}
__device__ __forceinline__ float tanhf_fast(float x) {
  return 1.0f - 2.0f * __builtin_amdgcn_rcpf(1.0f + __expf(2.0f * x));
}
// round-to-nearest-even fp32 -> bf16 bits; also returns the bf16 value as fp32
__device__ __forceinline__ ushort_t bf16_rne(float f, float* back) {
  unsigned u = __float_as_uint(f);
  unsigned r = u + 0x7fffu + ((u >> 16) & 1u);
  ushort_t h = (ushort_t)(r >> 16);
  *back = __uint_as_float((unsigned)h << 16);
  return h;
}
__device__ __forceinline__ void split_bf16(float f, ushort_t* hi, ushort_t* lo) {
  float fhi, d;
  *hi = bf16_rne(f, &fhi);
  *lo = bf16_rne(f - fhi, &d);
}

// ---------------- prep: split weights into bf16 hi/lo ----------------
__global__ __launch_bounds__(256) void prep_weights(
    const float* __restrict__ Whh0, const float* __restrict__ Whh1,
    const float* __restrict__ Wih0,
    ushort_t* __restrict__ w0h, ushort_t* __restrict__ w0l,
    ushort_t* __restrict__ w1h, ushort_t* __restrict__ w1l,
    ushort_t* __restrict__ wxh, ushort_t* __restrict__ wxl)
{
  const int idx = blockIdx.x * 256 + threadIdx.x;
  if (idx < 512 * HDIM) {
    split_bf16(Whh0[idx], &w0h[idx], &w0l[idx]);
    split_bf16(Whh1[idx], &w1h[idx], &w1l[idx]);
  }
  if (idx < 512 * 32) {  // Wih0 zero-padded K=16 -> 32
    const int g = idx >> 5, k = idx & 31;
    const float f = (k < IN_DIM) ? Wih0[g * IN_DIM + k] : 0.0f;
    split_bf16(f, &wxh[idx], &wxl[idx]);
  }
}

// ---------------- Layer 0: persistent MFMA recurrent kernel ----------------
// 256 WGs x 512 threads (8 waves). WG owns batches {2w,2w+1} (M-rows 0,1 of a
// padded 16-row MFMA tile). Whh0/Wih0 hi/lo B-fragments live in VGPRs.
__global__ __launch_bounds__(512, 2) void lstm_l0(
    const float* __restrict__ x,
    const ushort_t* __restrict__ Wh_hi, const ushort_t* __restrict__ Wh_lo,
    const ushort_t* __restrict__ Wx_hi, const ushort_t* __restrict__ Wx_lo,
    const float* __restrict__ bih, const float* __restrict__ bhh,
    float* __restrict__ h1state, float* __restrict__ c1state,
    float* __restrict__ h1buf, int t0, int Tc)
{
  const int tid  = threadIdx.x;
  const int wg   = blockIdx.x;
  const int lane = tid & 63;
  const int wv   = tid >> 6;      // wave 0..7, owns gates [wv*64, wv*64+64)
  const int row  = lane & 15;     // A-row / B-col / C-col
  const int kq   = lane >> 4;     // k quarter

  // persistent B fragments: 4 N-tiles x (4 h K-tiles + 1 x K-tile), hi+lo
  bf16x8 Bh[4][4], Bl[4][4], Bxh[4], Bxl[4];
#pragma unroll
  for (int i = 0; i < 4; ++i) {
    const int col = wv * 64 + i * 16 + row;
#pragma unroll
    for (int kt = 0; kt < 4; ++kt) {
      const int off = col * HDIM + kt * 32 + kq * 8;
      Bh[i][kt] = *(const bf16x8*)&Wh_hi[off];
      Bl[i][kt] = *(const bf16x8*)&Wh_lo[off];
    }
    const int xoff = col * 32 + kq * 8;
    Bxh[i] = *(const bf16x8*)&Wx_hi[xoff];
    Bxl[i] = *(const bf16x8*)&Wx_lo[xoff];
  }

  __shared__ __align__(16) ushort_t hfrag[2][16][136];  // [hi/lo][row][k], 272B stride
  __shared__ __align__(16) ushort_t xfrag[2][16][40];   // [hi/lo][row][k], 80B stride
  __shared__ __align__(16) float xs[2][64][IN_DIM];     // fp32 x window
  __shared__ __align__(16) float gs[2][G4];

  const int bb = tid >> 7;   // update-phase batch (tid<256)
  const int j  = tid & 127;  // update-phase hidden idx
  float bz[4] = {0, 0, 0, 0};
  float c = 0.0f, hcur = 0.0f;

  // zero fragment LDS (rows 2..15 stay zero forever)
  for (int idx = tid; idx < 2 * 16 * 136; idx += 512) ((ushort_t*)hfrag)[idx] = 0;
  for (int idx = tid; idx < 2 * 16 * 40; idx += 512) ((ushort_t*)xfrag)[idx] = 0;
  // stage initial 64-step x window
  {
    const int tb = t0 & ~63;
    const int sb = tid >> 8;
    const int f  = (tid & 255) * 4;
    const int ts = f >> 4, ii = f & 15;
    *(float4*)&xs[sb][ts][ii] =
        *(const float4*)&x[((size_t)(wg * 2 + sb) * T_SEQ + (tb + ts)) * IN_DIM + ii];
  }
  __syncthreads();
  if (tid < 256) {
#pragma unroll
    for (int q = 0; q < 4; ++q) bz[q] = bih[q * 128 + j] + bhh[q * 128 + j];
    const int bg = wg * 2 + bb;
    hcur = h1state[(size_t)bg * HDIM + j];
    c    = c1state[(size_t)bg * HDIM + j];
    split_bf16(hcur, &hfrag[0][bb][j], &hfrag[1][bb][j]);
  }
  if (tid < 32) {
    const int b = tid >> 4, k = tid & 15;
    split_bf16(xs[b][t0 & 63][k], &xfrag[0][b][k], &xfrag[1][b][k]);
  }
  __syncthreads();

  for (int tt = 0; tt < Tc; ++tt) {
    const int t = t0 + tt;
    // ---- MFMA phase: gates = [h; x] . W^T (hi/lo 3-term) ----
    f32x4 acc[4];
#pragma unroll
    for (int i = 0; i < 4; ++i) acc[i] = (f32x4){0.f, 0.f, 0.f, 0.f};
#pragma unroll
    for (int kt = 0; kt < 4; ++kt) {
      const bf16x8 ah = *(const bf16x8*)&hfrag[0][row][kt * 32 + kq * 8];
      const bf16x8 al = *(const bf16x8*)&hfrag[1][row][kt * 32 + kq * 8];
#pragma unroll
      for (int i = 0; i < 4; ++i) acc[i] = MFMA(ah, Bh[i][kt], acc[i]);
#pragma unroll
      for (int i = 0; i < 4; ++i) acc[i] = MFMA(ah, Bl[i][kt], acc[i]);
#pragma unroll
      for (int i = 0; i < 4; ++i) acc[i] = MFMA(al, Bh[i][kt], acc[i]);
    }
    {
      const bf16x8 axh = *(const bf16x8*)&xfrag[0][row][kq * 8];
      const bf16x8 axl = *(const bf16x8*)&xfrag[1][row][kq * 8];
#pragma unroll
      for (int i = 0; i < 4; ++i) acc[i] = MFMA(axh, Bxh[i], acc[i]);
#pragma unroll
      for (int i = 0; i < 4; ++i) acc[i] = MFMA(axh, Bxl[i], acc[i]);
#pragma unroll
      for (int i = 0; i < 4; ++i) acc[i] = MFMA(axl, Bxh[i], acc[i]);
    }
    if (kq == 0) {  // C rows 0,1 = batches
#pragma unroll
      for (int i = 0; i < 4; ++i) {
        const int g = wv * 64 + i * 16 + row;
        gs[0][g] = acc[i][0];
        gs[1][g] = acc[i][1];
      }
    }
    __syncthreads();

    // ---- update phase ----
    const bool needStage = (((t + 1) & 63) == 0) && (t + 1 < T_SEQ);
    if (tid < 256) {
      const float zi = gs[bb][j]       + bz[0];
      const float zf = gs[bb][128 + j] + bz[1];
      const float zg = gs[bb][256 + j] + bz[2];
      const float zo = gs[bb][384 + j] + bz[3];
      const float ig = sigf(zi), fg = sigf(zf);
      const float gg = tanhf_fast(zg), og = sigf(zo);
      c = fg * c + ig * gg;
      hcur = og * tanhf_fast(c);
      split_bf16(hcur, &hfrag[0][bb][j], &hfrag[1][bb][j]);
      h1buf[((size_t)tt * NBATCH + (wg * 2 + bb)) * HDIM + j] = hcur;
    } else if (needStage) {
      const int u  = tid - 256;
      const int tb = t + 1;
#pragma unroll
      for (int q = 0; q < 2; ++q) {
        const int f  = (q * 256 + u) * 4;
        const int sb = f >> 10;
        const int ff = f & 1023;
        const int ts = ff >> 4, ii = ff & 15;
        *(float4*)&xs[sb][ts][ii] =
            *(const float4*)&x[((size_t)(wg * 2 + sb) * T_SEQ + (tb + ts)) * IN_DIM + ii];
      }
    }
    if (needStage) __syncthreads();
    if (tid < 32 && tt + 1 < Tc) {
      const int b = tid >> 4, k = tid & 15;
      split_bf16(xs[b][(t + 1) & 63][k], &xfrag[0][b][k], &xfrag[1][b][k]);
    }
    __syncthreads();
  }

  if (tid < 256) {
    const int bg = wg * 2 + bb;
    h1state[(size_t)bg * HDIM + j] = hcur;
    c1state[(size_t)bg * HDIM + j] = c;
  }
}

// ---------------- gx1 GEMM (unchanged from R2) ----------------
#define BM 128
#define BN 64
#define BK 32

__global__ __launch_bounds__(256, 4) void gemm_gx1(
    const float* __restrict__ h1buf, const float* __restrict__ Wih1,
    const float* __restrict__ bih1, const float* __restrict__ bhh1,
    float* __restrict__ gx1buf)
{
  const int u  = threadIdx.x;
  const int tx = u & 15;
  const int ty = u >> 4;
  const size_t m0 = (size_t)(blockIdx.x >> 3) * BM;
  const int    n0 = (blockIdx.x & 7) * BN;

  __shared__ __align__(16) float As[BK][132];
  __shared__ __align__(16) float Bs[BK][68];

  float acc[8][4] = {};

  for (int k0 = 0; k0 < HDIM; k0 += BK) {
    __syncthreads();
#pragma unroll
    for (int jj = 0; jj < 4; ++jj) {
      const int f  = jj * 256 + u;
      const int m  = f >> 3;
      const int k4 = (f & 7) * 4;
      const float4 v = *(const float4*)&h1buf[(m0 + m) * HDIM + k0 + k4];
      As[k4 + 0][m] = v.x; As[k4 + 1][m] = v.y;
      As[k4 + 2][m] = v.z; As[k4 + 3][m] = v.w;
    }
#pragma unroll
    for (int jj = 0; jj < 2; ++jj) {
      const int f  = jj * 256 + u;
      const int g  = f >> 3;
      const int k4 = (f & 7) * 4;
      const float4 v = *(const float4*)&Wih1[(size_t)(n0 + g) * HDIM + k0 + k4];
      Bs[k4 + 0][g] = v.x; Bs[k4 + 1][g] = v.y;
      Bs[k4 + 2][g] = v.z; Bs[k4 + 3][g] = v.w;
    }
    __syncthreads();

#pragma unroll 4
    for (int k = 0; k < BK; ++k) {
      const float4 b  = *(const float4*)&Bs[k][tx * 4];
      const float4 a0 = *(const float4*)&As[k][ty * 8];
      const float4 a1 = *(const float4*)&As[k][ty * 8 + 4];
      const float av[8] = {a0.x, a0.y, a0.z, a0.w, a1.x, a1.y, a1.z, a1.w};
      const float bv[4] = {b.x, b.y, b.z, b.w};
#pragma unroll
      for (int i = 0; i < 8; ++i)
#pragma unroll
        for (int q = 0; q < 4; ++q)
          acc[i][q] += av[i] * bv[q];
    }
  }

  const float4 b1 = *(const float4*)&bih1[n0 + tx * 4];
  const float4 b2 = *(const float4*)&bhh1[n0 + tx * 4];
  const float bias[4] = {b1.x + b2.x, b1.y + b2.y, b1.z + b2.z, b1.w + b2.w};

#pragma unroll
  for (int i = 0; i < 8; ++i) {
    float4 o;
    o.x = acc[i][0] + bias[0];
    o.y = acc[i][1] + bias[1];
    o.z = acc[i][2] + bias[2];
    o.w = acc[i][3] + bias[3];
    *(float4*)&gx1buf[(m0 + ty * 8 + i) * G4 + n0 + tx * 4] = o;
  }
}

// ---------------- Layer 1 (MFMA) + fused FC ----------------
__global__ __launch_bounds__(512, 2) void lstm_l1(
    const float* __restrict__ gx1buf,
    const ushort_t* __restrict__ Wh_hi, const ushort_t* __restrict__ Wh_lo,
    const float* __restrict__ Wfc, const float* __restrict__ bfc,
    float* __restrict__ h2state, float* __restrict__ c2state,
    float* __restrict__ out, int t0, int Tc)
{
  const int tid  = threadIdx.x;
  const int wg   = blockIdx.x;
  const int lane = tid & 63;
  const int wv   = tid >> 6;
  const int row  = lane & 15;
  const int kq   = lane >> 4;

  bf16x8 Bh[4][4], Bl[4][4];
#pragma unroll
  for (int i = 0; i < 4; ++i) {
    const int col = wv * 64 + i * 16 + row;
#pragma unroll
    for (int kt = 0; kt < 4; ++kt) {
      const int off = col * HDIM + kt * 32 + kq * 8;
      Bh[i][kt] = *(const bf16x8*)&Wh_hi[off];
      Bl[i][kt] = *(const bf16x8*)&Wh_lo[off];
    }
  }

  __shared__ __align__(16) ushort_t hfrag[2][16][136];
  __shared__ __align__(16) float gs[2][G4];
  __shared__ float pl[4];

  const int bb = tid >> 7;
  const int j  = tid & 127;
  float c = 0.0f, hcur = 0.0f, wfc = 0.0f;
  const float bfcv = bfc[0];

  for (int idx = tid; idx < 2 * 16 * 136; idx += 512) ((ushort_t*)hfrag)[idx] = 0;
  __syncthreads();
  float zc[4] = {0, 0, 0, 0};
  if (tid < 256) {
    const int bg = wg * 2 + bb;
    hcur = h2state[(size_t)bg * HDIM + j];
    c    = c2state[(size_t)bg * HDIM + j];
    wfc  = Wfc[j];
    split_bf16(hcur, &hfrag[0][bb][j], &hfrag[1][bb][j]);
#pragma unroll
    for (int q = 0; q < 4; ++q)
      zc[q] = gx1buf[((size_t)0 * NBATCH + wg * 2 + bb) * G4 + q * 128 + j];
  }
  __syncthreads();

  for (int tt = 0; tt < Tc; ++tt) {
    f32x4 acc[4];
#pragma unroll
    for (int i = 0; i < 4; ++i) acc[i] = (f32x4){0.f, 0.f, 0.f, 0.f};
#pragma unroll
    for (int kt = 0; kt < 4; ++kt) {
      const bf16x8 ah = *(const bf16x8*)&hfrag[0][row][kt * 32 + kq * 8];
      const bf16x8 al = *(const bf16x8*)&hfrag[1][row][kt * 32 + kq * 8];
#pragma unroll
      for (int i = 0; i < 4; ++i) acc[i] = MFMA(ah, Bh[i][kt], acc[i]);
#pragma unroll
      for (int i = 0; i < 4; ++i) acc[i] = MFMA(ah, Bl[i][kt], acc[i]);
#pragma unroll
      for (int i = 0; i < 4; ++i) acc[i] = MFMA(al, Bh[i][kt], acc[i]);
    }
    if (kq == 0) {
#pragma unroll
      for (int i = 0; i < 4; ++i) {
        const int g = wv * 64 + i * 16 + row;
        gs[0][g] = acc[i][0];
        gs[1][g] = acc[i][1];
      }
    }
    __syncthreads();

    if (tid < 256) {
      const float zi = gs[bb][j]       + zc[0];
      const float zf = gs[bb][128 + j] + zc[1];
      const float zg = gs[bb][256 + j] + zc[2];
      const float zo = gs[bb][384 + j] + zc[3];
      const float ig = sigf(zi), fg = sigf(zf);
      const float gg = tanhf_fast(zg), og = sigf(zo);
      c = fg * c + ig * gg;
      hcur = og * tanhf_fast(c);
      split_bf16(hcur, &hfrag[0][bb][j], &hfrag[1][bb][j]);
      if (tt + 1 < Tc) {
#pragma unroll
        for (int q = 0; q < 4; ++q)
          zc[q] = gx1buf[((size_t)(tt + 1) * NBATCH + wg * 2 + bb) * G4 + q * 128 + j];
      }
      float p = fmaxf(hcur, 0.0f) * wfc;
#pragma unroll
      for (int off = 32; off; off >>= 1) p += __shfl_down(p, off);
      if ((tid & 63) == 0) pl[tid >> 6] = p;
    }
    __syncthreads();

    if (tid < 2) {
      const float o = pl[2 * tid] + pl[2 * tid + 1] + bfcv;
      out[(size_t)(wg * 2 + tid) * T_SEQ + (t0 + tt)] = fmaxf(o, 0.0f);
    }
  }

  if (tid < 256) {
    const int bg = wg * 2 + bb;
    h2state[(size_t)bg * HDIM + j] = hcur;
    c2state[(size_t)bg * HDIM + j] = c;
  }
}

extern "C" void kernel_launch(void* const* d_in, const int* in_sizes, int n_in,
                              void* d_out, int out_size, void* d_ws, size_t ws_size,
                              hipStream_t stream)
{
  const float* x    = (const float*)d_in[0];
  const float* Wih0 = (const float*)d_in[1];
  const float* Whh0 = (const float*)d_in[2];
  const float* bih0 = (const float*)d_in[3];
  const float* bhh0 = (const float*)d_in[4];
  const float* Wih1 = (const float*)d_in[5];
  const float* Whh1 = (const float*)d_in[6];
  const float* bih1 = (const float*)d_in[7];
  const float* bhh1 = (const float*)d_in[8];
  const float* Wfc  = (const float*)d_in[9];
  const float* bfc  = (const float*)d_in[10];
  float* out = (float*)d_out;

  const size_t stateN = (size_t)NBATCH * HDIM;  // 65536
  float* h1s = (float*)d_ws;
  float* c1s = h1s + stateN;
  float* h2s = c1s + stateN;
  float* c2s = h2s + stateN;
  ushort_t* w0h = (ushort_t*)(c2s + stateN);
  ushort_t* w0l = w0h + stateN;
  ushort_t* w1h = w0l + stateN;
  ushort_t* w1l = w1h + stateN;
  ushort_t* wxh = w1l + stateN;
  ushort_t* wxl = wxh + 512 * 32;
  float* h1buf  = (float*)(wxl + 512 * 32);
  const size_t fixedBytes =
      4 * stateN * sizeof(float) + (4 * stateN + 2 * 512 * 32) * sizeof(ushort_t);

  int Tc = 128;
  while (Tc > 1) {
    const size_t need =
        fixedBytes + (size_t)Tc * NBATCH * (HDIM + G4) * sizeof(float);
    if (need <= ws_size) break;
    Tc >>= 1;
  }
  float* gx1buf = h1buf + (size_t)Tc * NBATCH * HDIM;

  hipLaunchKernelGGL(prep_weights, dim3(256), dim3(256), 0, stream,
                     Whh0, Whh1, Wih0, w0h, w0l, w1h, w1l, wxh, wxl);
  hipMemsetAsync(d_ws, 0, 4 * stateN * sizeof(float), stream);

  for (int t0 = 0; t0 < T_SEQ; t0 += Tc) {
    hipLaunchKernelGGL(lstm_l0, dim3(NBATCH / 2), dim3(512), 0, stream,
                       x, w0h, w0l, wxh, wxl, bih0, bhh0, h1s, c1s, h1buf, t0, Tc);
    hipLaunchKernelGGL(gemm_gx1, dim3((Tc * NBATCH / BM) * (G4 / BN)),
                       dim3(256), 0, stream,
                       h1buf, Wih1, bih1, bhh1, gx1buf);
    hipLaunchKernelGGL(lstm_l1, dim3(NBATCH / 2), dim3(512), 0, stream,
                       gx1buf, w1h, w1l, Wfc, bfc, h2s, c2s, out, t0, Tc);
  }
}